// Round 8
// baseline (119.093 us; speedup 1.0000x reference)
//
#include <hip/hip_runtime.h>
#include <math.h>

#define N_SEQ 2048
#define DIMC 512
#define INNER 256
#define C2F (0.17677669529663687f * 1.4426950408889634f)  // scale * log2(e)
#define C2F2 (C2F * C2F)

typedef short bf16x8 __attribute__((ext_vector_type(8)));
typedef float f32x4 __attribute__((ext_vector_type(4)));

// ws layout (bytes):
//  ushort units: Q [0,2M): [bh][g:4][n:2048][8]   K [2M,4M): same
//                Vt [4M,6M): [bh][c:256][d:32][8]
//  q2*C2F2 @12MB, k2*C2F2 @12.25MB
//  att16 bf16 @13MB..17MB [b][n][256]
//  xt16 @21MB..29MB   wq16 @29MB..29.75MB   wo16 @30MB..30.25MB

static __device__ __forceinline__ ushort f2bf(float f) {
    uint x = __float_as_uint(f);
    x += 0x7fff + ((x >> 16) & 1);
    return (ushort)(x >> 16);
}
static __device__ __forceinline__ float bf2f(ushort u) {
    return __uint_as_float(((uint)u) << 16);
}
static __device__ __forceinline__ float fast_exp2_neg(float x) {  // exp2(-x)
    float r; asm("v_exp_f32 %0, -%1" : "=v"(r) : "v"(x)); return r;
}
static __device__ __forceinline__ float fast_sqrt(float x) {
    float r; asm("v_sqrt_f32 %0, %1" : "=v"(r) : "v"(x)); return r;
}

// ---------------------------------------------------------------------------
// x [b][c][n] f32 -> xt [b][n][c] bf16
// ---------------------------------------------------------------------------
__global__ void xpose_cvt(const float* __restrict__ x, ushort* __restrict__ xt) {
    __shared__ __align__(16) ushort T[64][72];
    const int b = blockIdx.z;
    const int c0 = blockIdx.y * 64;
    const int n0 = blockIdx.x * 64;
    const int t = threadIdx.x;
    const int cl = t >> 4;
    const int n4 = (t & 15) * 4;
    const float* xb = x + ((size_t)b * DIMC + c0) * N_SEQ + n0;
#pragma unroll
    for (int cc = 0; cc < 4; ++cc) {
        const int c = cl + cc * 16;
        float4 v = *(const float4*)(xb + (size_t)c * N_SEQ + n4);
        T[n4 + 0][c] = f2bf(v.x);
        T[n4 + 1][c] = f2bf(v.y);
        T[n4 + 2][c] = f2bf(v.z);
        T[n4 + 3][c] = f2bf(v.w);
    }
    __syncthreads();
    const int nl = t >> 2;
    const int c16 = (t & 3) * 16;
    uint4 v0 = *(const uint4*)&T[nl][c16];
    uint4 v1 = *(const uint4*)&T[nl][c16 + 8];
    ushort* dst = xt + ((size_t)b * N_SEQ + n0 + nl) * DIMC + c0 + c16;
    *(uint4*)dst = v0;
    *(uint4*)(dst + 8) = v1;
}

__global__ void wcvt2(const float* __restrict__ wq, const float* __restrict__ wo,
                      ushort* __restrict__ wq16, ushort* __restrict__ wo16) {
    const int bid = blockIdx.x;
    if (bid < 384) {
        int i = (bid * 256 + threadIdx.x) * 4;
        float4 v = *(const float4*)(wq + i);
        ushort4 p;
        p.x = f2bf(v.x); p.y = f2bf(v.y); p.z = f2bf(v.z); p.w = f2bf(v.w);
        *(ushort4*)(wq16 + i) = p;
    } else {
        int i = ((bid - 384) * 256 + threadIdx.x) * 4;
        float4 v = *(const float4*)(wo + i);
        ushort4 p;
        p.x = f2bf(v.x); p.y = f2bf(v.y); p.z = f2bf(v.z); p.w = f2bf(v.w);
        *(ushort4*)(wo16 + i) = p;
    }
}

// ---------------------------------------------------------------------------
// QKV projection, bf16 MFMA. 64x64 tile, BK=32, 4 waves.
// ---------------------------------------------------------------------------
__global__ __launch_bounds__(256) void qkv_mfma(const ushort* __restrict__ xt,
        const ushort* __restrict__ w16, ushort* __restrict__ ws16) {
    __shared__ __align__(16) ushort Wls[4 * 520];
    __shared__ __align__(16) ushort Xls[4 * 520];
    const int b = blockIdx.z;
    const int o0 = blockIdx.y * 64;
    const int n0 = blockIdx.x * 64;
    const int t = threadIdx.x;
    const int l = t & 63, w = t >> 6;
    const int q15 = l & 15, g = l >> 4;
    f32x4 acc[4];
#pragma unroll
    for (int nn = 0; nn < 4; ++nn) acc[nn] = (f32x4){0.f, 0.f, 0.f, 0.f};
    const int srow = t >> 2, sg = t & 3;
    const ushort* wsrc = w16 + (size_t)(o0 + srow) * DIMC + sg * 8;
    const ushort* xsrc = xt + ((size_t)b * N_SEQ + n0 + srow) * DIMC + sg * 8;
    uint4 wreg = *(const uint4*)wsrc;
    uint4 xreg = *(const uint4*)xsrc;
    for (int k0 = 0; k0 < DIMC; k0 += 32) {
        __builtin_amdgcn_s_barrier();
        __builtin_amdgcn_sched_barrier(0);
        *(uint4*)(Wls + sg * 520 + srow * 8) = wreg;
        *(uint4*)(Xls + sg * 520 + srow * 8) = xreg;
        if (k0 + 32 < DIMC) {
            wreg = *(const uint4*)(wsrc + k0 + 32);
            xreg = *(const uint4*)(xsrc + k0 + 32);
        }
        asm volatile("s_waitcnt lgkmcnt(0)" ::: "memory");
        __builtin_amdgcn_s_barrier();
        __builtin_amdgcn_sched_barrier(0);
        bf16x8 af = *(const bf16x8*)(Wls + g * 520 + (16 * w + q15) * 8);
        __builtin_amdgcn_s_setprio(1);
#pragma unroll
        for (int nn = 0; nn < 4; ++nn) {
            bf16x8 bfr = *(const bf16x8*)(Xls + g * 520 + (16 * nn + q15) * 8);
            acc[nn] = __builtin_amdgcn_mfma_f32_16x16x32_bf16(af, bfr, acc[nn], 0, 0, 0);
        }
        __builtin_amdgcn_s_setprio(0);
    }
    const int oatom = o0 + 16 * w;
    const int t_idx = oatom >> 8;
    const int h = (oatom >> 5) & 7;
    const int bh = b * 8 + h;
    const int d0 = (oatom & 31) + 4 * g;
    if (t_idx < 2) {
        ushort* dst = ws16 + (size_t)t_idx * 2097152 + (size_t)bh * 65536
                      + (size_t)(d0 >> 3) * 16384 + (d0 & 7);
#pragma unroll
        for (int nn = 0; nn < 4; ++nn) {
            const int n_ = n0 + 16 * nn + q15;
            ushort4 p;
            p.x = f2bf(acc[nn][0]); p.y = f2bf(acc[nn][1]);
            p.z = f2bf(acc[nn][2]); p.w = f2bf(acc[nn][3]);
            *(ushort4*)(dst + (size_t)n_ * 8) = p;
        }
    } else {
        ushort* dst = ws16 + (size_t)4194304 + (size_t)bh * 65536;
#pragma unroll
        for (int nn = 0; nn < 4; ++nn) {
            const int n_ = n0 + 16 * nn + q15;
            ushort* dd = dst + (size_t)(n_ >> 3) * 256 + (n_ & 7);
            dd[(d0 + 0) * 8] = f2bf(acc[nn][0]);
            dd[(d0 + 1) * 8] = f2bf(acc[nn][1]);
            dd[(d0 + 2) * 8] = f2bf(acc[nn][2]);
            dd[(d0 + 3) * 8] = f2bf(acc[nn][3]);
        }
    }
}

// ---------------------------------------------------------------------------
// q2/k2 from bf16 values, prescaled by C2F^2
// ---------------------------------------------------------------------------
__global__ void sq_kernel(const ushort* __restrict__ ws16, float* __restrict__ q2,
                          float* __restrict__ k2) {
    const int which = blockIdx.y;
    const int idx = blockIdx.x * 256 + threadIdx.x;
    const int bh = idx >> 11, n = idx & 2047;
    const ushort* base = ws16 + (size_t)which * 2097152 + (size_t)bh * 65536
                         + (size_t)n * 8;
    float s = 0.f;
#pragma unroll
    for (int g = 0; g < 4; ++g) {
        uint4 v = *(const uint4*)(base + (size_t)g * 16384);
        uint a[4] = {v.x, v.y, v.z, v.w};
#pragma unroll
        for (int e = 0; e < 4; ++e) {
            float lo = bf2f((ushort)(a[e] & 0xffff));
            float hi = bf2f((ushort)(a[e] >> 16));
            s += lo * lo + hi * hi;
        }
    }
    (which == 0 ? q2 : k2)[idx] = s * (float)C2F2;
}

// ---------------------------------------------------------------------------
// Flash L2 attention, 2-deep software pipeline (prefetch next tile's K/V/k2
// fragments while computing current tile). m=0 fixed softmax shift (exact).
// ---------------------------------------------------------------------------
static __device__ __forceinline__ void load_tile(
        const ushort* __restrict__ Kfrag, const ushort* __restrict__ Vfrag,
        const float* __restrict__ k2p, int j0,
        bf16x8 (&kf)[8], bf16x8 (&vf)[8], float4 (&kk)[8]) {
#pragma unroll
    for (int k = 0; k < 8; ++k)
        kf[k] = *(const bf16x8*)(Kfrag + ((size_t)j0 + 16 * k) * 8);
#pragma unroll
    for (int jc = 0; jc < 4; ++jc) {
        vf[jc * 2 + 0] = *(const bf16x8*)(Vfrag + (size_t)j0 * 32 + jc * 1024);
        vf[jc * 2 + 1] = *(const bf16x8*)(Vfrag + (size_t)j0 * 32 + jc * 1024 + 128);
    }
#pragma unroll
    for (int k = 0; k < 8; ++k)
        kk[k] = *(const float4*)(k2p + j0 + 16 * k);
}

static __device__ __forceinline__ void compute_tile(
        const bf16x8 (&kf)[8], const bf16x8 (&vf)[8], const float4 (&kk)[8],
        float q2v, bf16x8 qf, f32x4 (&accO)[2], float& lsm,
        ushort* __restrict__ plane, int g) {
    const f32x4 zz = (f32x4){0.f, 0.f, 0.f, 0.f};
    f32x4 st[8];
    __builtin_amdgcn_s_setprio(1);
#pragma unroll
    for (int k = 0; k < 8; ++k)
        st[k] = __builtin_amdgcn_mfma_f32_16x16x32_bf16(kf[k], qf, zz, 0, 0, 0);
    __builtin_amdgcn_s_setprio(0);
    float lt = 0.f;
#pragma unroll
    for (int k = 0; k < 8; ++k) {
        float ka[4] = {kk[k].x, kk[k].y, kk[k].z, kk[k].w};
        float p[4];
#pragma unroll
        for (int r = 0; r < 4; ++r) {
            float a = q2v + ka[r];
            float d2 = fmaf(-2.f * (float)C2F2, st[k][r], a);
            p[r] = fast_exp2_neg(fast_sqrt(fmaxf(d2, 1e-12f)));
        }
        lt += (p[0] + p[1]) + (p[2] + p[3]);
        uint pk0, pk1;
        asm("v_cvt_pk_bf16_f32 %0, %1, %2" : "=v"(pk0) : "v"(p[0]), "v"(p[1]));
        asm("v_cvt_pk_bf16_f32 %0, %1, %2" : "=v"(pk1) : "v"(p[2]), "v"(p[3]));
        uint2 pv; pv.x = pk0; pv.y = pk1;
        *(uint2*)(plane + 16 * k + 4 * g) = pv;
    }
    lsm += lt;
    __builtin_amdgcn_s_setprio(1);
#pragma unroll
    for (int jc = 0; jc < 4; ++jc) {
        bf16x8 pf = *(const bf16x8*)(plane + 32 * jc + 8 * g);
        accO[0] = __builtin_amdgcn_mfma_f32_16x16x32_bf16(vf[jc * 2 + 0], pf, accO[0], 0, 0, 0);
        accO[1] = __builtin_amdgcn_mfma_f32_16x16x32_bf16(vf[jc * 2 + 1], pf, accO[1], 0, 0, 0);
    }
    __builtin_amdgcn_s_setprio(0);
}

__global__ __launch_bounds__(256) void attn_kernel(
        const ushort* __restrict__ ws16, const float* __restrict__ q2g,
        const float* __restrict__ k2g, ushort* __restrict__ att16) {
    __shared__ __align__(16) ushort Pls[4][16][140];
    const int bid = blockIdx.x;                   // 1024 blocks
    const int sw = (bid & 7) * 128 + (bid >> 3);  // bijective XCD swizzle
    const int q0 = (sw & 31) * 64;
    const int bh = sw >> 5;
    const int b = bh >> 3, h = bh & 7;
    const int tid = threadIdx.x;
    const int l = tid & 63;
    const int w = tid >> 6;
    const int q15 = l & 15;
    const int g = l >> 4;
    const int qrow = q0 + 16 * w + q15;

    const ushort* Qbh = ws16 + (size_t)bh * 65536;
    const ushort* Kfrag = ws16 + 2097152 + (size_t)bh * 65536
                          + (size_t)g * 16384 + (size_t)q15 * 8;
    const ushort* Vfrag = ws16 + 4194304 + (size_t)bh * 65536
                          + (size_t)g * 256 + (size_t)q15 * 8;
    const float* k2p = k2g + (size_t)bh * 2048 + 4 * g;

    const bf16x8 qf = *(const bf16x8*)(Qbh + (size_t)g * 16384 + (size_t)qrow * 8);
    const float q2v = q2g[(size_t)bh * 2048 + qrow];
    ushort* plane = &Pls[w][q15][0];

    f32x4 accO[2];
    accO[0] = (f32x4){0.f, 0.f, 0.f, 0.f};
    accO[1] = (f32x4){0.f, 0.f, 0.f, 0.f};
    float lsm = 0.f;

    bf16x8 kfA[8], vfA[8], kfB[8], vfB[8];
    float4 kkA[8], kkB[8];

    load_tile(Kfrag, Vfrag, k2p, 0, kfA, vfA, kkA);
#pragma unroll 1
    for (int t = 0; t < 16; t += 2) {
        load_tile(Kfrag, Vfrag, k2p, (t + 1) * 128, kfB, vfB, kkB);
        compute_tile(kfA, vfA, kkA, q2v, qf, accO, lsm, plane, g);
        if (t + 2 < 16)
            load_tile(Kfrag, Vfrag, k2p, (t + 2) * 128, kfA, vfA, kkA);
        compute_tile(kfB, vfB, kkB, q2v, qf, accO, lsm, plane, g);
    }

    lsm += __shfl_xor(lsm, 16);
    lsm += __shfl_xor(lsm, 32);
    const float invl = 1.f / lsm;
    ushort* dst = att16 + ((size_t)(b * N_SEQ + qrow)) * INNER + h * 32 + 4 * g;
#pragma unroll
    for (int d = 0; d < 2; ++d) {
        ushort4 o;
        o.x = f2bf(accO[d][0] * invl); o.y = f2bf(accO[d][1] * invl);
        o.z = f2bf(accO[d][2] * invl); o.w = f2bf(accO[d][3] * invl);
        *(ushort4*)(dst + d * 16) = o;
    }
}

// ---------------------------------------------------------------------------
// Output projection, bf16 MFMA
// ---------------------------------------------------------------------------
__global__ __launch_bounds__(256) void out_mfma(const ushort* __restrict__ att16,
        const ushort* __restrict__ wo16, const float* __restrict__ bias,
        float* __restrict__ out) {
    __shared__ __align__(16) ushort Wls[4 * 520];
    __shared__ __align__(16) ushort Als[4 * 520];
    const int b = blockIdx.z;
    const int o0 = blockIdx.y * 64;
    const int n0 = blockIdx.x * 64;
    const int t = threadIdx.x;
    const int l = t & 63, w = t >> 6;
    const int q15 = l & 15, g = l >> 4;
    f32x4 acc[4];
#pragma unroll
    for (int nn = 0; nn < 4; ++nn) acc[nn] = (f32x4){0.f, 0.f, 0.f, 0.f};
    const int srow = t >> 2, sg = t & 3;
    const ushort* wsrc = wo16 + (size_t)(o0 + srow) * INNER + sg * 8;
    const ushort* asrc = att16 + ((size_t)b * N_SEQ + n0 + srow) * INNER + sg * 8;
    uint4 wreg = *(const uint4*)wsrc;
    uint4 areg = *(const uint4*)asrc;
    for (int k0 = 0; k0 < INNER; k0 += 32) {
        __builtin_amdgcn_s_barrier();
        __builtin_amdgcn_sched_barrier(0);
        *(uint4*)(Wls + sg * 520 + srow * 8) = wreg;
        *(uint4*)(Als + sg * 520 + srow * 8) = areg;
        if (k0 + 32 < INNER) {
            wreg = *(const uint4*)(wsrc + k0 + 32);
            areg = *(const uint4*)(asrc + k0 + 32);
        }
        asm volatile("s_waitcnt lgkmcnt(0)" ::: "memory");
        __builtin_amdgcn_s_barrier();
        __builtin_amdgcn_sched_barrier(0);
        bf16x8 af = *(const bf16x8*)(Wls + g * 520 + (16 * w + q15) * 8);
        __builtin_amdgcn_s_setprio(1);
#pragma unroll
        for (int nn = 0; nn < 4; ++nn) {
            bf16x8 bfr = *(const bf16x8*)(Als + g * 520 + (16 * nn + q15) * 8);
            acc[nn] = __builtin_amdgcn_mfma_f32_16x16x32_bf16(af, bfr, acc[nn], 0, 0, 0);
        }
        __builtin_amdgcn_s_setprio(0);
    }
    const int obase = o0 + 16 * w + 4 * g;
    float4 bi = *(const float4*)(bias + obase);
    float* ob = out + ((size_t)b * DIMC + obase) * N_SEQ;
#pragma unroll
    for (int nn = 0; nn < 4; ++nn) {
        const int n_ = n0 + 16 * nn + q15;
        ob[0 * N_SEQ + n_] = acc[nn][0] + bi.x;
        ob[1 * N_SEQ + n_] = acc[nn][1] + bi.y;
        ob[2 * N_SEQ + n_] = acc[nn][2] + bi.z;
        ob[3 * N_SEQ + n_] = acc[nn][3] + bi.w;
    }
}

extern "C" void kernel_launch(void* const* d_in, const int* in_sizes, int n_in,
                              void* d_out, int out_size, void* d_ws, size_t ws_size,
                              hipStream_t stream) {
    const float* x = (const float*)d_in[0];
    const float* w_qkv = (const float*)d_in[1];
    const float* w_out = (const float*)d_in[2];
    const float* b_out = (const float*)d_in[3];
    ushort* ws16 = (ushort*)d_ws;
    float* q2f = (float*)((char*)d_ws + (12 << 20));
    float* k2f = (float*)((char*)d_ws + (12 << 20) + (256 << 10));
    ushort* att16 = (ushort*)((char*)d_ws + (13 << 20));
    ushort* xt16 = (ushort*)((char*)d_ws + (21 << 20));
    ushort* wq16 = (ushort*)((char*)d_ws + (29 << 20));
    ushort* wo16 = (ushort*)((char*)d_ws + (30 << 20));
    float* out = (float*)d_out;

    xpose_cvt<<<dim3(32, 8, 4), 256, 0, stream>>>(x, xt16);
    wcvt2<<<dim3(512), 256, 0, stream>>>(w_qkv, w_out, wq16, wo16);
    qkv_mfma<<<dim3(32, 12, 4), 256, 0, stream>>>(xt16, wq16, ws16);
    sq_kernel<<<dim3(256, 2), 256, 0, stream>>>(ws16, q2f, k2f);
    attn_kernel<<<dim3(1024), 256, 0, stream>>>(ws16, q2f, k2f, att16);
    out_mfma<<<dim3(32, 8, 4), 256, 0, stream>>>(att16, wo16, b_out, out);
}

// Round 9
// 112.346 us; speedup vs baseline: 1.0601x; 1.0601x over previous
//
#include <hip/hip_runtime.h>
#include <math.h>

#define N_SEQ 2048
#define DIMC 512
#define INNER 256
#define C2F (0.17677669529663687f * 1.4426950408889634f)  // scale * log2(e)
#define C2F2 (C2F * C2F)

typedef short bf16x8 __attribute__((ext_vector_type(8)));
typedef float f32x4 __attribute__((ext_vector_type(4)));

// ws layout (bytes):
//  ushort units: Q [0,2M): [bh][g:4][n:2048][8]   K [2M,4M): same
//                Vt [4M,6M): [bh][c:256][d:32][8]
//  q2*C2F2 @12MB, k2*C2F2 @12.25MB
//  att16 bf16 @13MB..17MB [b][n][256]
//  xt16 @21MB..29MB   wq16 @29MB..29.75MB   wo16 @30MB..30.25MB

static __device__ __forceinline__ ushort f2bf(float f) {
    uint x = __float_as_uint(f);
    x += 0x7fff + ((x >> 16) & 1);
    return (ushort)(x >> 16);
}
static __device__ __forceinline__ float bf2f(ushort u) {
    return __uint_as_float(((uint)u) << 16);
}
static __device__ __forceinline__ float fast_exp2_neg(float x) {  // exp2(-x)
    float r; asm("v_exp_f32 %0, -%1" : "=v"(r) : "v"(x)); return r;
}
static __device__ __forceinline__ float fast_sqrt(float x) {
    float r; asm("v_sqrt_f32 %0, %1" : "=v"(r) : "v"(x)); return r;
}

// ---------------------------------------------------------------------------
// x [b][c][n] f32 -> xt [b][n][c] bf16
// ---------------------------------------------------------------------------
__global__ void xpose_cvt(const float* __restrict__ x, ushort* __restrict__ xt) {
    __shared__ __align__(16) ushort T[64][72];
    const int b = blockIdx.z;
    const int c0 = blockIdx.y * 64;
    const int n0 = blockIdx.x * 64;
    const int t = threadIdx.x;
    const int cl = t >> 4;
    const int n4 = (t & 15) * 4;
    const float* xb = x + ((size_t)b * DIMC + c0) * N_SEQ + n0;
#pragma unroll
    for (int cc = 0; cc < 4; ++cc) {
        const int c = cl + cc * 16;
        float4 v = *(const float4*)(xb + (size_t)c * N_SEQ + n4);
        T[n4 + 0][c] = f2bf(v.x);
        T[n4 + 1][c] = f2bf(v.y);
        T[n4 + 2][c] = f2bf(v.z);
        T[n4 + 3][c] = f2bf(v.w);
    }
    __syncthreads();
    const int nl = t >> 2;
    const int c16 = (t & 3) * 16;
    uint4 v0 = *(const uint4*)&T[nl][c16];
    uint4 v1 = *(const uint4*)&T[nl][c16 + 8];
    ushort* dst = xt + ((size_t)b * N_SEQ + n0 + nl) * DIMC + c0 + c16;
    *(uint4*)dst = v0;
    *(uint4*)(dst + 8) = v1;
}

__global__ void wcvt2(const float* __restrict__ wq, const float* __restrict__ wo,
                      ushort* __restrict__ wq16, ushort* __restrict__ wo16) {
    const int bid = blockIdx.x;
    if (bid < 384) {
        int i = (bid * 256 + threadIdx.x) * 4;
        float4 v = *(const float4*)(wq + i);
        ushort4 p;
        p.x = f2bf(v.x); p.y = f2bf(v.y); p.z = f2bf(v.z); p.w = f2bf(v.w);
        *(ushort4*)(wq16 + i) = p;
    } else {
        int i = ((bid - 384) * 256 + threadIdx.x) * 4;
        float4 v = *(const float4*)(wo + i);
        ushort4 p;
        p.x = f2bf(v.x); p.y = f2bf(v.y); p.z = f2bf(v.z); p.w = f2bf(v.w);
        *(ushort4*)(wo16 + i) = p;
    }
}

// ---------------------------------------------------------------------------
// QKV projection, bf16 MFMA. 64x64 tile, BK=32, 4 waves.
// ---------------------------------------------------------------------------
__global__ __launch_bounds__(256) void qkv_mfma(const ushort* __restrict__ xt,
        const ushort* __restrict__ w16, ushort* __restrict__ ws16) {
    __shared__ __align__(16) ushort Wls[4 * 520];
    __shared__ __align__(16) ushort Xls[4 * 520];
    const int b = blockIdx.z;
    const int o0 = blockIdx.y * 64;
    const int n0 = blockIdx.x * 64;
    const int t = threadIdx.x;
    const int l = t & 63, w = t >> 6;
    const int q15 = l & 15, g = l >> 4;
    f32x4 acc[4];
#pragma unroll
    for (int nn = 0; nn < 4; ++nn) acc[nn] = (f32x4){0.f, 0.f, 0.f, 0.f};
    const int srow = t >> 2, sg = t & 3;
    const ushort* wsrc = w16 + (size_t)(o0 + srow) * DIMC + sg * 8;
    const ushort* xsrc = xt + ((size_t)b * N_SEQ + n0 + srow) * DIMC + sg * 8;
    uint4 wreg = *(const uint4*)wsrc;
    uint4 xreg = *(const uint4*)xsrc;
    for (int k0 = 0; k0 < DIMC; k0 += 32) {
        __builtin_amdgcn_s_barrier();
        __builtin_amdgcn_sched_barrier(0);
        *(uint4*)(Wls + sg * 520 + srow * 8) = wreg;
        *(uint4*)(Xls + sg * 520 + srow * 8) = xreg;
        if (k0 + 32 < DIMC) {
            wreg = *(const uint4*)(wsrc + k0 + 32);
            xreg = *(const uint4*)(xsrc + k0 + 32);
        }
        asm volatile("s_waitcnt lgkmcnt(0)" ::: "memory");
        __builtin_amdgcn_s_barrier();
        __builtin_amdgcn_sched_barrier(0);
        bf16x8 af = *(const bf16x8*)(Wls + g * 520 + (16 * w + q15) * 8);
        __builtin_amdgcn_s_setprio(1);
#pragma unroll
        for (int nn = 0; nn < 4; ++nn) {
            bf16x8 bfr = *(const bf16x8*)(Xls + g * 520 + (16 * nn + q15) * 8);
            acc[nn] = __builtin_amdgcn_mfma_f32_16x16x32_bf16(af, bfr, acc[nn], 0, 0, 0);
        }
        __builtin_amdgcn_s_setprio(0);
    }
    const int oatom = o0 + 16 * w;
    const int t_idx = oatom >> 8;
    const int h = (oatom >> 5) & 7;
    const int bh = b * 8 + h;
    const int d0 = (oatom & 31) + 4 * g;
    if (t_idx < 2) {
        ushort* dst = ws16 + (size_t)t_idx * 2097152 + (size_t)bh * 65536
                      + (size_t)(d0 >> 3) * 16384 + (d0 & 7);
#pragma unroll
        for (int nn = 0; nn < 4; ++nn) {
            const int n_ = n0 + 16 * nn + q15;
            ushort4 p;
            p.x = f2bf(acc[nn][0]); p.y = f2bf(acc[nn][1]);
            p.z = f2bf(acc[nn][2]); p.w = f2bf(acc[nn][3]);
            *(ushort4*)(dst + (size_t)n_ * 8) = p;
        }
    } else {
        ushort* dst = ws16 + (size_t)4194304 + (size_t)bh * 65536;
#pragma unroll
        for (int nn = 0; nn < 4; ++nn) {
            const int n_ = n0 + 16 * nn + q15;
            ushort* dd = dst + (size_t)(n_ >> 3) * 256 + (n_ & 7);
            dd[(d0 + 0) * 8] = f2bf(acc[nn][0]);
            dd[(d0 + 1) * 8] = f2bf(acc[nn][1]);
            dd[(d0 + 2) * 8] = f2bf(acc[nn][2]);
            dd[(d0 + 3) * 8] = f2bf(acc[nn][3]);
        }
    }
}

// ---------------------------------------------------------------------------
// q2/k2 from bf16 values, prescaled by C2F^2
// ---------------------------------------------------------------------------
__global__ void sq_kernel(const ushort* __restrict__ ws16, float* __restrict__ q2,
                          float* __restrict__ k2) {
    const int which = blockIdx.y;
    const int idx = blockIdx.x * 256 + threadIdx.x;
    const int bh = idx >> 11, n = idx & 2047;
    const ushort* base = ws16 + (size_t)which * 2097152 + (size_t)bh * 65536
                         + (size_t)n * 8;
    float s = 0.f;
#pragma unroll
    for (int g = 0; g < 4; ++g) {
        uint4 v = *(const uint4*)(base + (size_t)g * 16384);
        uint a[4] = {v.x, v.y, v.z, v.w};
#pragma unroll
        for (int e = 0; e < 4; ++e) {
            float lo = bf2f((ushort)(a[e] & 0xffff));
            float hi = bf2f((ushort)(a[e] >> 16));
            s += lo * lo + hi * hi;
        }
    }
    (which == 0 ? q2 : k2)[idx] = s * (float)C2F2;
}

// ---------------------------------------------------------------------------
// Flash L2 attention. LDS double-buffered K/V/k2 staging via reg-relay:
// each wave issues its 4x16B share of tile t+1 at the top of tile t, computes
// tile t entirely from LDS, then vmcnt(0) (loads landed under ~2000cyc of
// compute) + ds_write + ONE __syncthreads per tile. No mid-pipeline drain.
// L2 traffic /4 (4 waves share the staged tile). Row-sum via ones-MFMA.
// m=0 fixed softmax shift (exact by shift-invariance).
// ---------------------------------------------------------------------------
__global__ __launch_bounds__(256) void attn_kernel(
        const ushort* __restrict__ ws16, const float* __restrict__ q2g,
        const float* __restrict__ k2g, ushort* __restrict__ att16) {
    // K plane stride 1032 ush (2064B): banks g*16 mod 128 -> spread. buf stride 4128.
    // V chunk stride 520 ush (1040B): 2-way alias only (free).    buf stride 4160.
    __shared__ __align__(16) ushort Kls[2][4 * 1032];
    __shared__ __align__(16) ushort Vls[2][8 * 520];
    __shared__ __align__(16) float k2ls[2][128];
    __shared__ __align__(16) ushort Pls[4][16][140];

    const int bid = blockIdx.x;                   // 1024 blocks
    const int sw = (bid & 7) * 128 + (bid >> 3);  // bijective XCD swizzle
    const int q0 = (sw & 31) * 64;
    const int bh = sw >> 5;
    const int b = bh >> 3, h = bh & 7;
    const int tid = threadIdx.x;
    const int l = tid & 63;
    const int w = tid >> 6;
    const int q15 = l & 15;
    const int g = l >> 4;
    const int qrow = q0 + 16 * w + q15;
    const bool wl32 = (tid < 32);

    const ushort* Qbh = ws16 + (size_t)bh * 65536;
    const ushort* Kbh = ws16 + 2097152 + (size_t)bh * 65536;
    const ushort* Vbh = ws16 + 4194304 + (size_t)bh * 65536;
    const float* k2bh = k2g + (size_t)bh * 2048;

    // staging op assignment: ops {w, w+4, w+8, w+12}; op<8 -> K(g=op>>1,c2=op&1),
    // op>=8 -> V(chunk=op-8). src += j*mult; dst += p*halfstride.
#define OP_SETUP(i, BS, MU, PD, HS)                                            \
    {                                                                          \
        const int opi = w + 4 * (i);                                           \
        if (opi < 8) {                                                         \
            BS = Kbh + (opi >> 1) * 16384 + (opi & 1) * 512 + l * 8;           \
            MU = 8;                                                            \
            PD = &Kls[0][0] + (opi >> 1) * 1032 + (opi & 1) * 512 + l * 8;     \
            HS = 4128;                                                         \
        } else {                                                               \
            BS = Vbh + (opi - 8) * 512 + l * 8;                                \
            MU = 32;                                                           \
            PD = &Vls[0][0] + (opi - 8) * 520 + l * 8;                         \
            HS = 4160;                                                         \
        }                                                                      \
    }
    const ushort* bs0; int mu0; ushort* pd0; int hs0;
    const ushort* bs1; int mu1; ushort* pd1; int hs1;
    const ushort* bs2; int mu2; ushort* pd2; int hs2;
    const ushort* bs3; int mu3; ushort* pd3; int hs3;
    OP_SETUP(0, bs0, mu0, pd0, hs0)
    OP_SETUP(1, bs1, mu1, pd1, hs1)
    OP_SETUP(2, bs2, mu2, pd2, hs2)
    OP_SETUP(3, bs3, mu3, pd3, hs3)
#undef OP_SETUP

    // prologue: stage tile 0 into buffer 0 + load Q/q2
    {
        uint4 s0 = *(const uint4*)bs0;
        uint4 s1 = *(const uint4*)bs1;
        uint4 s2 = *(const uint4*)bs2;
        uint4 s3 = *(const uint4*)bs3;
        uint4 sk2 = {0, 0, 0, 0};
        if (wl32) sk2 = *(const uint4*)(k2bh + (l << 2));
        asm volatile("s_waitcnt vmcnt(0)" ::: "memory");
        *(uint4*)pd0 = s0;
        *(uint4*)pd1 = s1;
        *(uint4*)pd2 = s2;
        *(uint4*)pd3 = s3;
        if (wl32) *(uint4*)(&k2ls[0][l << 2]) = sk2;
    }
    const bf16x8 qf = *(const bf16x8*)(Qbh + (size_t)g * 16384 + (size_t)qrow * 8);
    const float q2v = q2g[(size_t)bh * 2048 + qrow];
    bf16x8 onesv;
#pragma unroll
    for (int e = 0; e < 8; ++e) onesv[e] = (short)0x3F80;
    ushort* plane = &Pls[w][q15][0];
    __syncthreads();

    f32x4 accO[2];
    accO[0] = (f32x4){0.f, 0.f, 0.f, 0.f};
    accO[1] = (f32x4){0.f, 0.f, 0.f, 0.f};
    f32x4 accS = (f32x4){0.f, 0.f, 0.f, 0.f};

#pragma unroll 1
    for (int t = 0; t < 16; ++t) {
        const int p = t & 1;
        const ushort* KlsP = &Kls[0][0] + p * 4128;
        const ushort* VlsP = &Vls[0][0] + p * 4160;
        const float* k2lsP = &k2ls[p][0];

        // issue next tile's global loads (land under this tile's compute)
        uint4 r0, r1, r2, r3, rk2;
        if (t < 15) {
            const int j1 = (t + 1) * 128;
            r0 = *(const uint4*)(bs0 + (size_t)j1 * mu0);
            r1 = *(const uint4*)(bs1 + (size_t)j1 * mu1);
            r2 = *(const uint4*)(bs2 + (size_t)j1 * mu2);
            r3 = *(const uint4*)(bs3 + (size_t)j1 * mu3);
            if (wl32) rk2 = *(const uint4*)(k2bh + j1 + (l << 2));
        }
        __builtin_amdgcn_sched_barrier(0);

        // ---- compute tile t from LDS ----
        bf16x8 kf[8];
        float4 kk[8];
#pragma unroll
        for (int k = 0; k < 8; ++k)
            kf[k] = *(const bf16x8*)(KlsP + g * 1032 + (16 * k + q15) * 8);
#pragma unroll
        for (int k = 0; k < 8; ++k)
            kk[k] = *(const float4*)(k2lsP + 16 * k + 4 * g);

        const f32x4 zz = (f32x4){0.f, 0.f, 0.f, 0.f};
        f32x4 st[8];
        __builtin_amdgcn_s_setprio(1);
#pragma unroll
        for (int k = 0; k < 8; ++k)
            st[k] = __builtin_amdgcn_mfma_f32_16x16x32_bf16(kf[k], qf, zz, 0, 0, 0);
        __builtin_amdgcn_s_setprio(0);

#pragma unroll
        for (int k = 0; k < 8; ++k) {
            float ka[4] = {kk[k].x, kk[k].y, kk[k].z, kk[k].w};
            float pr[4];
#pragma unroll
            for (int r = 0; r < 4; ++r) {
                float a = q2v + ka[r];
                float d2 = fmaf(-2.f * (float)C2F2, st[k][r], a);
                pr[r] = fast_exp2_neg(fast_sqrt(fmaxf(d2, 1e-12f)));
            }
            uint pk0, pk1;
            asm("v_cvt_pk_bf16_f32 %0, %1, %2" : "=v"(pk0) : "v"(pr[0]), "v"(pr[1]));
            asm("v_cvt_pk_bf16_f32 %0, %1, %2" : "=v"(pk1) : "v"(pr[2]), "v"(pr[3]));
            uint2 pv; pv.x = pk0; pv.y = pk1;
            *(uint2*)(plane + 16 * k + 4 * g) = pv;
        }

        __builtin_amdgcn_s_setprio(1);
#pragma unroll
        for (int jc = 0; jc < 4; ++jc) {
            bf16x8 pf = *(const bf16x8*)(plane + 32 * jc + 8 * g);
            const int c = 4 * jc + g;
            const ushort* vb = VlsP + (c >> 1) * 520 + (c & 1) * 256 + q15 * 8;
            bf16x8 vf0 = *(const bf16x8*)(vb);
            bf16x8 vf1 = *(const bf16x8*)(vb + 128);
            accO[0] = __builtin_amdgcn_mfma_f32_16x16x32_bf16(vf0, pf, accO[0], 0, 0, 0);
            accO[1] = __builtin_amdgcn_mfma_f32_16x16x32_bf16(vf1, pf, accO[1], 0, 0, 0);
            accS = __builtin_amdgcn_mfma_f32_16x16x32_bf16(onesv, pf, accS, 0, 0, 0);
        }
        __builtin_amdgcn_s_setprio(0);

        // ---- relay staged regs into the other LDS buffer ----
        asm volatile("s_waitcnt vmcnt(0)" ::: "memory");
        if (t < 15) {
            const int p1 = p ^ 1;
            *(uint4*)(pd0 + p1 * hs0) = r0;
            *(uint4*)(pd1 + p1 * hs1) = r1;
            *(uint4*)(pd2 + p1 * hs2) = r2;
            *(uint4*)(pd3 + p1 * hs3) = r3;
            if (wl32) *(uint4*)(&k2ls[p1][l << 2]) = rk2;
        }
        __syncthreads();
    }

    const float invl = 1.f / accS[0];   // row-sum of P over all j (ones-MFMA)
    ushort* dst = att16 + ((size_t)(b * N_SEQ + qrow)) * INNER + h * 32 + 4 * g;
#pragma unroll
    for (int d = 0; d < 2; ++d) {
        ushort4 o;
        o.x = f2bf(accO[d][0] * invl); o.y = f2bf(accO[d][1] * invl);
        o.z = f2bf(accO[d][2] * invl); o.w = f2bf(accO[d][3] * invl);
        *(ushort4*)(dst + d * 16) = o;
    }
}

// ---------------------------------------------------------------------------
// Output projection, bf16 MFMA
// ---------------------------------------------------------------------------
__global__ __launch_bounds__(256) void out_mfma(const ushort* __restrict__ att16,
        const ushort* __restrict__ wo16, const float* __restrict__ bias,
        float* __restrict__ out) {
    __shared__ __align__(16) ushort Wls[4 * 520];
    __shared__ __align__(16) ushort Als[4 * 520];
    const int b = blockIdx.z;
    const int o0 = blockIdx.y * 64;
    const int n0 = blockIdx.x * 64;
    const int t = threadIdx.x;
    const int l = t & 63, w = t >> 6;
    const int q15 = l & 15, g = l >> 4;
    f32x4 acc[4];
#pragma unroll
    for (int nn = 0; nn < 4; ++nn) acc[nn] = (f32x4){0.f, 0.f, 0.f, 0.f};
    const int srow = t >> 2, sg = t & 3;
    const ushort* wsrc = wo16 + (size_t)(o0 + srow) * INNER + sg * 8;
    const ushort* asrc = att16 + ((size_t)b * N_SEQ + n0 + srow) * INNER + sg * 8;
    uint4 wreg = *(const uint4*)wsrc;
    uint4 areg = *(const uint4*)asrc;
    for (int k0 = 0; k0 < INNER; k0 += 32) {
        __builtin_amdgcn_s_barrier();
        __builtin_amdgcn_sched_barrier(0);
        *(uint4*)(Wls + sg * 520 + srow * 8) = wreg;
        *(uint4*)(Als + sg * 520 + srow * 8) = areg;
        if (k0 + 32 < INNER) {
            wreg = *(const uint4*)(wsrc + k0 + 32);
            areg = *(const uint4*)(asrc + k0 + 32);
        }
        asm volatile("s_waitcnt lgkmcnt(0)" ::: "memory");
        __builtin_amdgcn_s_barrier();
        __builtin_amdgcn_sched_barrier(0);
        bf16x8 af = *(const bf16x8*)(Wls + g * 520 + (16 * w + q15) * 8);
        __builtin_amdgcn_s_setprio(1);
#pragma unroll
        for (int nn = 0; nn < 4; ++nn) {
            bf16x8 bfr = *(const bf16x8*)(Als + g * 520 + (16 * nn + q15) * 8);
            acc[nn] = __builtin_amdgcn_mfma_f32_16x16x32_bf16(af, bfr, acc[nn], 0, 0, 0);
        }
        __builtin_amdgcn_s_setprio(0);
    }
    const int obase = o0 + 16 * w + 4 * g;
    float4 bi = *(const float4*)(bias + obase);
    float* ob = out + ((size_t)b * DIMC + obase) * N_SEQ;
#pragma unroll
    for (int nn = 0; nn < 4; ++nn) {
        const int n_ = n0 + 16 * nn + q15;
        ob[0 * N_SEQ + n_] = acc[nn][0] + bi.x;
        ob[1 * N_SEQ + n_] = acc[nn][1] + bi.y;
        ob[2 * N_SEQ + n_] = acc[nn][2] + bi.z;
        ob[3 * N_SEQ + n_] = acc[nn][3] + bi.w;
    }
}

extern "C" void kernel_launch(void* const* d_in, const int* in_sizes, int n_in,
                              void* d_out, int out_size, void* d_ws, size_t ws_size,
                              hipStream_t stream) {
    const float* x = (const float*)d_in[0];
    const float* w_qkv = (const float*)d_in[1];
    const float* w_out = (const float*)d_in[2];
    const float* b_out = (const float*)d_in[3];
    ushort* ws16 = (ushort*)d_ws;
    float* q2f = (float*)((char*)d_ws + (12 << 20));
    float* k2f = (float*)((char*)d_ws + (12 << 20) + (256 << 10));
    ushort* att16 = (ushort*)((char*)d_ws + (13 << 20));
    ushort* xt16 = (ushort*)((char*)d_ws + (21 << 20));
    ushort* wq16 = (ushort*)((char*)d_ws + (29 << 20));
    ushort* wo16 = (ushort*)((char*)d_ws + (30 << 20));
    float* out = (float*)d_out;

    xpose_cvt<<<dim3(32, 8, 4), 256, 0, stream>>>(x, xt16);
    wcvt2<<<dim3(512), 256, 0, stream>>>(w_qkv, w_out, wq16, wo16);
    qkv_mfma<<<dim3(32, 12, 4), 256, 0, stream>>>(xt16, wq16, ws16);
    sq_kernel<<<dim3(256, 2), 256, 0, stream>>>(ws16, q2f, k2f);
    attn_kernel<<<dim3(1024), 256, 0, stream>>>(ws16, q2f, k2f, att16);
    out_mfma<<<dim3(32, 8, 4), 256, 0, stream>>>(att16, wo16, b_out, out);
}

// Round 10
// 91.507 us; speedup vs baseline: 1.3015x; 1.2277x over previous
//
#include <hip/hip_runtime.h>
#include <math.h>

#define N_SEQ 2048
#define DIMC 512
#define INNER 256
#define C2F (0.17677669529663687f * 1.4426950408889634f)  // scale * log2(e)
#define C2F2 (C2F * C2F)

typedef short bf16x8 __attribute__((ext_vector_type(8)));
typedef float f32x4 __attribute__((ext_vector_type(4)));

// ws layout (bytes):
//  ushort units: Q [0,2M): [bh][g:4][n:2048][8]   K [2M,4M): same
//                Vt [4M,6M): [bh][c:256][d:32][8]
//  k2*C2F2 @12.25MB
//  att16 bf16 @13MB..17MB [b][n][256]
//  xt16 @21MB..29MB   wq16 @29MB..29.75MB   wo16 @30MB..30.25MB

static __device__ __forceinline__ ushort f2bf(float f) {
    uint x = __float_as_uint(f);
    x += 0x7fff + ((x >> 16) & 1);
    return (ushort)(x >> 16);
}
static __device__ __forceinline__ float bf2f(ushort u) {
    return __uint_as_float(((uint)u) << 16);
}
static __device__ __forceinline__ float fast_exp2_neg(float x) {  // exp2(-x)
    float r; asm("v_exp_f32 %0, -%1" : "=v"(r) : "v"(x)); return r;
}
static __device__ __forceinline__ float fast_sqrt(float x) {
    float r; asm("v_sqrt_f32 %0, %1" : "=v"(r) : "v"(x)); return r;
}

// ---------------------------------------------------------------------------
// x [b][c][n] f32 -> xt [b][n][c] bf16
// ---------------------------------------------------------------------------
__global__ void xpose_cvt(const float* __restrict__ x, ushort* __restrict__ xt) {
    __shared__ __align__(16) ushort T[64][72];
    const int b = blockIdx.z;
    const int c0 = blockIdx.y * 64;
    const int n0 = blockIdx.x * 64;
    const int t = threadIdx.x;
    const int cl = t >> 4;
    const int n4 = (t & 15) * 4;
    const float* xb = x + ((size_t)b * DIMC + c0) * N_SEQ + n0;
#pragma unroll
    for (int cc = 0; cc < 4; ++cc) {
        const int c = cl + cc * 16;
        float4 v = *(const float4*)(xb + (size_t)c * N_SEQ + n4);
        T[n4 + 0][c] = f2bf(v.x);
        T[n4 + 1][c] = f2bf(v.y);
        T[n4 + 2][c] = f2bf(v.z);
        T[n4 + 3][c] = f2bf(v.w);
    }
    __syncthreads();
    const int nl = t >> 2;
    const int c16 = (t & 3) * 16;
    uint4 v0 = *(const uint4*)&T[nl][c16];
    uint4 v1 = *(const uint4*)&T[nl][c16 + 8];
    ushort* dst = xt + ((size_t)b * N_SEQ + n0 + nl) * DIMC + c0 + c16;
    *(uint4*)dst = v0;
    *(uint4*)(dst + 8) = v1;
}

__global__ void wcvt2(const float* __restrict__ wq, const float* __restrict__ wo,
                      ushort* __restrict__ wq16, ushort* __restrict__ wo16) {
    const int bid = blockIdx.x;
    if (bid < 384) {
        int i = (bid * 256 + threadIdx.x) * 4;
        float4 v = *(const float4*)(wq + i);
        ushort4 p;
        p.x = f2bf(v.x); p.y = f2bf(v.y); p.z = f2bf(v.z); p.w = f2bf(v.w);
        *(ushort4*)(wq16 + i) = p;
    } else {
        int i = ((bid - 384) * 256 + threadIdx.x) * 4;
        float4 v = *(const float4*)(wo + i);
        ushort4 p;
        p.x = f2bf(v.x); p.y = f2bf(v.y); p.z = f2bf(v.z); p.w = f2bf(v.w);
        *(ushort4*)(wo16 + i) = p;
    }
}

// ---------------------------------------------------------------------------
// QKV projection, bf16 MFMA. 64x64 tile, BK=32, 4 waves.
// ---------------------------------------------------------------------------
__global__ __launch_bounds__(256) void qkv_mfma(const ushort* __restrict__ xt,
        const ushort* __restrict__ w16, ushort* __restrict__ ws16) {
    __shared__ __align__(16) ushort Wls[4 * 520];
    __shared__ __align__(16) ushort Xls[4 * 520];
    const int b = blockIdx.z;
    const int o0 = blockIdx.y * 64;
    const int n0 = blockIdx.x * 64;
    const int t = threadIdx.x;
    const int l = t & 63, w = t >> 6;
    const int q15 = l & 15, g = l >> 4;
    f32x4 acc[4];
#pragma unroll
    for (int nn = 0; nn < 4; ++nn) acc[nn] = (f32x4){0.f, 0.f, 0.f, 0.f};
    const int srow = t >> 2, sg = t & 3;
    const ushort* wsrc = w16 + (size_t)(o0 + srow) * DIMC + sg * 8;
    const ushort* xsrc = xt + ((size_t)b * N_SEQ + n0 + srow) * DIMC + sg * 8;
    uint4 wreg = *(const uint4*)wsrc;
    uint4 xreg = *(const uint4*)xsrc;
    for (int k0 = 0; k0 < DIMC; k0 += 32) {
        __builtin_amdgcn_s_barrier();
        __builtin_amdgcn_sched_barrier(0);
        *(uint4*)(Wls + sg * 520 + srow * 8) = wreg;
        *(uint4*)(Xls + sg * 520 + srow * 8) = xreg;
        if (k0 + 32 < DIMC) {
            wreg = *(const uint4*)(wsrc + k0 + 32);
            xreg = *(const uint4*)(xsrc + k0 + 32);
        }
        asm volatile("s_waitcnt lgkmcnt(0)" ::: "memory");
        __builtin_amdgcn_s_barrier();
        __builtin_amdgcn_sched_barrier(0);
        bf16x8 af = *(const bf16x8*)(Wls + g * 520 + (16 * w + q15) * 8);
        __builtin_amdgcn_s_setprio(1);
#pragma unroll
        for (int nn = 0; nn < 4; ++nn) {
            bf16x8 bfr = *(const bf16x8*)(Xls + g * 520 + (16 * nn + q15) * 8);
            acc[nn] = __builtin_amdgcn_mfma_f32_16x16x32_bf16(af, bfr, acc[nn], 0, 0, 0);
        }
        __builtin_amdgcn_s_setprio(0);
    }
    const int oatom = o0 + 16 * w;
    const int t_idx = oatom >> 8;
    const int h = (oatom >> 5) & 7;
    const int bh = b * 8 + h;
    const int d0 = (oatom & 31) + 4 * g;
    if (t_idx < 2) {
        ushort* dst = ws16 + (size_t)t_idx * 2097152 + (size_t)bh * 65536
                      + (size_t)(d0 >> 3) * 16384 + (d0 & 7);
#pragma unroll
        for (int nn = 0; nn < 4; ++nn) {
            const int n_ = n0 + 16 * nn + q15;
            ushort4 p;
            p.x = f2bf(acc[nn][0]); p.y = f2bf(acc[nn][1]);
            p.z = f2bf(acc[nn][2]); p.w = f2bf(acc[nn][3]);
            *(ushort4*)(dst + (size_t)n_ * 8) = p;
        }
    } else {
        ushort* dst = ws16 + (size_t)4194304 + (size_t)bh * 65536;
#pragma unroll
        for (int nn = 0; nn < 4; ++nn) {
            const int n_ = n0 + 16 * nn + q15;
            ushort* dd = dst + (size_t)(n_ >> 3) * 256 + (n_ & 7);
            dd[(d0 + 0) * 8] = f2bf(acc[nn][0]);
            dd[(d0 + 1) * 8] = f2bf(acc[nn][1]);
            dd[(d0 + 2) * 8] = f2bf(acc[nn][2]);
            dd[(d0 + 3) * 8] = f2bf(acc[nn][3]);
        }
    }
}

// ---------------------------------------------------------------------------
// k2 from bf16 values, prescaled by C2F^2 (q2 now computed inside attn)
// ---------------------------------------------------------------------------
__global__ void sq_kernel(const ushort* __restrict__ ws16, float* __restrict__ k2) {
    const int idx = blockIdx.x * 256 + threadIdx.x;
    const int bh = idx >> 11, n = idx & 2047;
    const ushort* base = ws16 + 2097152 + (size_t)bh * 65536 + (size_t)n * 8;
    float s = 0.f;
#pragma unroll
    for (int g = 0; g < 4; ++g) {
        uint4 v = *(const uint4*)(base + (size_t)g * 16384);
        uint a[4] = {v.x, v.y, v.z, v.w};
#pragma unroll
        for (int e = 0; e < 4; ++e) {
            float lo = bf2f((ushort)(a[e] & 0xffff));
            float hi = bf2f((ushort)(a[e] >> 16));
            s += lo * lo + hi * hi;
        }
    }
    k2[idx] = s * (float)C2F2;
}

// ---------------------------------------------------------------------------
// Flash L2 attention (R6 barrier-free structure) + half-tile kf prefetch.
// Only K fragments carry cross-half register liveness (+32 VGPR); kk/vfr are
// JIT (use-distance covers most latency). __launch_bounds__(256,4) caps VGPR
// at 128 so the grid-limited 4 waves/SIMD occupancy is preserved.
// m=0 fixed softmax shift (exact); row-sum via ones-MFMA (accS).
// ---------------------------------------------------------------------------
static __device__ __forceinline__ void load_kf(const ushort* __restrict__ Kf,
                                               int jh, bf16x8 (&kf)[4]) {
#pragma unroll
    for (int k = 0; k < 4; ++k)
        kf[k] = *(const bf16x8*)(Kf + (size_t)(jh + 16 * k) * 8);
}

static __device__ __forceinline__ void compute_half(
        const bf16x8 (&kf)[4], const ushort* __restrict__ Vf,
        const float* __restrict__ k2p, int jbase, int half, float q2v,
        bf16x8 qf, bf16x8 onesv, f32x4 (&accO)[2], f32x4& accS,
        ushort* __restrict__ plane, int g) {
    float4 kk[4];
#pragma unroll
    for (int k = 0; k < 4; ++k)
        kk[k] = *(const float4*)(k2p + jbase + half * 64 + 16 * k);
    bf16x8 vfr[4];
#pragma unroll
    for (int jc = 0; jc < 2; ++jc) {
        const int cl = 4 * (2 * half + jc) + g;
        vfr[jc * 2 + 0] = *(const bf16x8*)(Vf + (size_t)jbase * 32 + cl * 256);
        vfr[jc * 2 + 1] = *(const bf16x8*)(Vf + (size_t)jbase * 32 + cl * 256 + 128);
    }
    const f32x4 zz = (f32x4){0.f, 0.f, 0.f, 0.f};
    f32x4 st[4];
    __builtin_amdgcn_s_setprio(1);
#pragma unroll
    for (int k = 0; k < 4; ++k)
        st[k] = __builtin_amdgcn_mfma_f32_16x16x32_bf16(kf[k], qf, zz, 0, 0, 0);
    __builtin_amdgcn_s_setprio(0);
#pragma unroll
    for (int k = 0; k < 4; ++k) {
        float ka[4] = {kk[k].x, kk[k].y, kk[k].z, kk[k].w};
        float pr[4];
#pragma unroll
        for (int r = 0; r < 4; ++r) {
            float a = q2v + ka[r];
            float d2 = fmaf(-2.f * (float)C2F2, st[k][r], a);
            pr[r] = fast_exp2_neg(fast_sqrt(fmaxf(d2, 1e-12f)));
        }
        uint pk0, pk1;
        asm("v_cvt_pk_bf16_f32 %0, %1, %2" : "=v"(pk0) : "v"(pr[0]), "v"(pr[1]));
        asm("v_cvt_pk_bf16_f32 %0, %1, %2" : "=v"(pk1) : "v"(pr[2]), "v"(pr[3]));
        uint2 pv; pv.x = pk0; pv.y = pk1;
        *(uint2*)(plane + 16 * (4 * half + k) + 4 * g) = pv;
    }
    __builtin_amdgcn_s_setprio(1);
#pragma unroll
    for (int jc = 0; jc < 2; ++jc) {
        bf16x8 pf = *(const bf16x8*)(plane + 32 * (2 * half + jc) + 8 * g);
        accO[0] = __builtin_amdgcn_mfma_f32_16x16x32_bf16(vfr[jc * 2 + 0], pf, accO[0], 0, 0, 0);
        accO[1] = __builtin_amdgcn_mfma_f32_16x16x32_bf16(vfr[jc * 2 + 1], pf, accO[1], 0, 0, 0);
        accS = __builtin_amdgcn_mfma_f32_16x16x32_bf16(onesv, pf, accS, 0, 0, 0);
    }
    __builtin_amdgcn_s_setprio(0);
}

__global__ __launch_bounds__(256, 4) void attn_kernel(
        const ushort* __restrict__ ws16, const float* __restrict__ k2g,
        ushort* __restrict__ att16) {
    __shared__ __align__(16) ushort Pls[4][16][140];
    const int bid = blockIdx.x;                   // 1024 blocks
    const int sw = (bid & 7) * 128 + (bid >> 3);  // bijective XCD swizzle
    const int q0 = (sw & 31) * 64;
    const int bh = sw >> 5;
    const int b = bh >> 3, h = bh & 7;
    const int tid = threadIdx.x;
    const int l = tid & 63;
    const int w = tid >> 6;
    const int q15 = l & 15;
    const int g = l >> 4;
    const int qrow = q0 + 16 * w + q15;

    const ushort* Qbh = ws16 + (size_t)bh * 65536;
    const ushort* Kf = ws16 + 2097152 + (size_t)bh * 65536
                       + (size_t)g * 16384 + (size_t)q15 * 8;
    const ushort* Vf = ws16 + 4194304 + (size_t)bh * 65536 + (size_t)q15 * 8;
    const float* k2p = k2g + (size_t)bh * 2048 + 4 * g;

    const bf16x8 qf = *(const bf16x8*)(Qbh + (size_t)g * 16384 + (size_t)qrow * 8);
    // q2 in-register: dot(qf,qf) summed across the 4 g-lane groups
    float q2l = 0.f;
#pragma unroll
    for (int e = 0; e < 8; ++e) {
        float qe = bf2f((ushort)qf[e]);
        q2l = fmaf(qe, qe, q2l);
    }
    q2l += __shfl_xor(q2l, 16);
    q2l += __shfl_xor(q2l, 32);
    const float q2v = q2l * (float)C2F2;

    bf16x8 onesv;
#pragma unroll
    for (int e = 0; e < 8; ++e) onesv[e] = (short)0x3F80;
    ushort* plane = &Pls[w][q15][0];

    f32x4 accO[2];
    accO[0] = (f32x4){0.f, 0.f, 0.f, 0.f};
    accO[1] = (f32x4){0.f, 0.f, 0.f, 0.f};
    f32x4 accS = (f32x4){0.f, 0.f, 0.f, 0.f};

    bf16x8 kfA[4], kfB[4];
    load_kf(Kf, 0, kfA);
    load_kf(Kf, 64, kfB);
#pragma unroll 1
    for (int t = 0; t < 16; ++t) {
        const int jb = t * 128;
        compute_half(kfA, Vf, k2p, jb, 0, q2v, qf, onesv, accO, accS, plane, g);
        load_kf(Kf, jb + 128, kfA);      // next tile half A (overrun at t=15 is
        __builtin_amdgcn_sched_barrier(0);  // in-ws garbage, never consumed)
        compute_half(kfB, Vf, k2p, jb, 1, q2v, qf, onesv, accO, accS, plane, g);
        load_kf(Kf, jb + 192, kfB);
        __builtin_amdgcn_sched_barrier(0);
    }

    const float invl = 1.f / accS[0];   // row-sum of P over all j (ones-MFMA)
    ushort* dst = att16 + ((size_t)(b * N_SEQ + qrow)) * INNER + h * 32 + 4 * g;
#pragma unroll
    for (int d = 0; d < 2; ++d) {
        ushort4 o;
        o.x = f2bf(accO[d][0] * invl); o.y = f2bf(accO[d][1] * invl);
        o.z = f2bf(accO[d][2] * invl); o.w = f2bf(accO[d][3] * invl);
        *(ushort4*)(dst + d * 16) = o;
    }
}

// ---------------------------------------------------------------------------
// Output projection, bf16 MFMA
// ---------------------------------------------------------------------------
__global__ __launch_bounds__(256) void out_mfma(const ushort* __restrict__ att16,
        const ushort* __restrict__ wo16, const float* __restrict__ bias,
        float* __restrict__ out) {
    __shared__ __align__(16) ushort Wls[4 * 520];
    __shared__ __align__(16) ushort Als[4 * 520];
    const int b = blockIdx.z;
    const int o0 = blockIdx.y * 64;
    const int n0 = blockIdx.x * 64;
    const int t = threadIdx.x;
    const int l = t & 63, w = t >> 6;
    const int q15 = l & 15, g = l >> 4;
    f32x4 acc[4];
#pragma unroll
    for (int nn = 0; nn < 4; ++nn) acc[nn] = (f32x4){0.f, 0.f, 0.f, 0.f};
    const int srow = t >> 2, sg = t & 3;
    const ushort* wsrc = wo16 + (size_t)(o0 + srow) * INNER + sg * 8;
    const ushort* asrc = att16 + ((size_t)b * N_SEQ + n0 + srow) * INNER + sg * 8;
    uint4 wreg = *(const uint4*)wsrc;
    uint4 areg = *(const uint4*)asrc;
    for (int k0 = 0; k0 < INNER; k0 += 32) {
        __builtin_amdgcn_s_barrier();
        __builtin_amdgcn_sched_barrier(0);
        *(uint4*)(Wls + sg * 520 + srow * 8) = wreg;
        *(uint4*)(Als + sg * 520 + srow * 8) = areg;
        if (k0 + 32 < INNER) {
            wreg = *(const uint4*)(wsrc + k0 + 32);
            areg = *(const uint4*)(asrc + k0 + 32);
        }
        asm volatile("s_waitcnt lgkmcnt(0)" ::: "memory");
        __builtin_amdgcn_s_barrier();
        __builtin_amdgcn_sched_barrier(0);
        bf16x8 af = *(const bf16x8*)(Wls + g * 520 + (16 * w + q15) * 8);
        __builtin_amdgcn_s_setprio(1);
#pragma unroll
        for (int nn = 0; nn < 4; ++nn) {
            bf16x8 bfr = *(const bf16x8*)(Als + g * 520 + (16 * nn + q15) * 8);
            acc[nn] = __builtin_amdgcn_mfma_f32_16x16x32_bf16(af, bfr, acc[nn], 0, 0, 0);
        }
        __builtin_amdgcn_s_setprio(0);
    }
    const int obase = o0 + 16 * w + 4 * g;
    float4 bi = *(const float4*)(bias + obase);
    float* ob = out + ((size_t)b * DIMC + obase) * N_SEQ;
#pragma unroll
    for (int nn = 0; nn < 4; ++nn) {
        const int n_ = n0 + 16 * nn + q15;
        ob[0 * N_SEQ + n_] = acc[nn][0] + bi.x;
        ob[1 * N_SEQ + n_] = acc[nn][1] + bi.y;
        ob[2 * N_SEQ + n_] = acc[nn][2] + bi.z;
        ob[3 * N_SEQ + n_] = acc[nn][3] + bi.w;
    }
}

extern "C" void kernel_launch(void* const* d_in, const int* in_sizes, int n_in,
                              void* d_out, int out_size, void* d_ws, size_t ws_size,
                              hipStream_t stream) {
    const float* x = (const float*)d_in[0];
    const float* w_qkv = (const float*)d_in[1];
    const float* w_out = (const float*)d_in[2];
    const float* b_out = (const float*)d_in[3];
    ushort* ws16 = (ushort*)d_ws;
    float* k2f = (float*)((char*)d_ws + (12 << 20) + (256 << 10));
    ushort* att16 = (ushort*)((char*)d_ws + (13 << 20));
    ushort* xt16 = (ushort*)((char*)d_ws + (21 << 20));
    ushort* wq16 = (ushort*)((char*)d_ws + (29 << 20));
    ushort* wo16 = (ushort*)((char*)d_ws + (30 << 20));
    float* out = (float*)d_out;

    xpose_cvt<<<dim3(32, 8, 4), 256, 0, stream>>>(x, xt16);
    wcvt2<<<dim3(512), 256, 0, stream>>>(w_qkv, w_out, wq16, wo16);
    qkv_mfma<<<dim3(32, 12, 4), 256, 0, stream>>>(xt16, wq16, ws16);
    sq_kernel<<<dim3(256), 256, 0, stream>>>(ws16, k2f);
    attn_kernel<<<dim3(1024), 256, 0, stream>>>(ws16, k2f, att16);
    out_mfma<<<dim3(32, 8, 4), 256, 0, stream>>>(att16, wo16, b_out, out);
}

// Round 11
// 90.759 us; speedup vs baseline: 1.3122x; 1.0082x over previous
//
#include <hip/hip_runtime.h>
#include <math.h>

#define N_SEQ 2048
#define DIMC 512
#define INNER 256
#define C2F (0.17677669529663687f * 1.4426950408889634f)  // scale * log2(e)
#define C2F2 (C2F * C2F)

typedef short bf16x8 __attribute__((ext_vector_type(8)));
typedef float f32x4 __attribute__((ext_vector_type(4)));

// ws layout (bytes):
//  ushort units: Q [0,2M): [bh][g:4][n:2048][8]   K [2M,4M): same
//                Vt [4M,6M): [bh][c:256][d:32][8]
//  k2*C2F2 @12.25MB
//  att16 bf16 @13MB..17MB [b][n][256]
//  xt16 @21MB..29MB   wq16 @29MB..29.75MB   wo16 @30MB..30.25MB

static __device__ __forceinline__ ushort f2bf(float f) {
    uint x = __float_as_uint(f);
    x += 0x7fff + ((x >> 16) & 1);
    return (ushort)(x >> 16);
}
static __device__ __forceinline__ float bf2f(ushort u) {
    return __uint_as_float(((uint)u) << 16);
}
static __device__ __forceinline__ float fast_exp2_neg(float x) {  // exp2(-x)
    float r; asm("v_exp_f32 %0, -%1" : "=v"(r) : "v"(x)); return r;
}
static __device__ __forceinline__ float fast_sqrt(float x) {
    float r; asm("v_sqrt_f32 %0, %1" : "=v"(r) : "v"(x)); return r;
}

// ---------------------------------------------------------------------------
// x [b][c][n] f32 -> xt [b][n][c] bf16
// ---------------------------------------------------------------------------
__global__ void xpose_cvt(const float* __restrict__ x, ushort* __restrict__ xt) {
    __shared__ __align__(16) ushort T[64][72];
    const int b = blockIdx.z;
    const int c0 = blockIdx.y * 64;
    const int n0 = blockIdx.x * 64;
    const int t = threadIdx.x;
    const int cl = t >> 4;
    const int n4 = (t & 15) * 4;
    const float* xb = x + ((size_t)b * DIMC + c0) * N_SEQ + n0;
#pragma unroll
    for (int cc = 0; cc < 4; ++cc) {
        const int c = cl + cc * 16;
        float4 v = *(const float4*)(xb + (size_t)c * N_SEQ + n4);
        T[n4 + 0][c] = f2bf(v.x);
        T[n4 + 1][c] = f2bf(v.y);
        T[n4 + 2][c] = f2bf(v.z);
        T[n4 + 3][c] = f2bf(v.w);
    }
    __syncthreads();
    const int nl = t >> 2;
    const int c16 = (t & 3) * 16;
    uint4 v0 = *(const uint4*)&T[nl][c16];
    uint4 v1 = *(const uint4*)&T[nl][c16 + 8];
    ushort* dst = xt + ((size_t)b * N_SEQ + n0 + nl) * DIMC + c0 + c16;
    *(uint4*)dst = v0;
    *(uint4*)(dst + 8) = v1;
}

__global__ void wcvt2(const float* __restrict__ wq, const float* __restrict__ wo,
                      ushort* __restrict__ wq16, ushort* __restrict__ wo16) {
    const int bid = blockIdx.x;
    if (bid < 384) {
        int i = (bid * 256 + threadIdx.x) * 4;
        float4 v = *(const float4*)(wq + i);
        ushort4 p;
        p.x = f2bf(v.x); p.y = f2bf(v.y); p.z = f2bf(v.z); p.w = f2bf(v.w);
        *(ushort4*)(wq16 + i) = p;
    } else {
        int i = ((bid - 384) * 256 + threadIdx.x) * 4;
        float4 v = *(const float4*)(wo + i);
        ushort4 p;
        p.x = f2bf(v.x); p.y = f2bf(v.y); p.z = f2bf(v.z); p.w = f2bf(v.w);
        *(ushort4*)(wo16 + i) = p;
    }
}

// ---------------------------------------------------------------------------
// QKV projection, bf16 MFMA. 64x64 tile, BK=32, 4 waves.
// ---------------------------------------------------------------------------
__global__ __launch_bounds__(256) void qkv_mfma(const ushort* __restrict__ xt,
        const ushort* __restrict__ w16, ushort* __restrict__ ws16) {
    __shared__ __align__(16) ushort Wls[4 * 520];
    __shared__ __align__(16) ushort Xls[4 * 520];
    const int b = blockIdx.z;
    const int o0 = blockIdx.y * 64;
    const int n0 = blockIdx.x * 64;
    const int t = threadIdx.x;
    const int l = t & 63, w = t >> 6;
    const int q15 = l & 15, g = l >> 4;
    f32x4 acc[4];
#pragma unroll
    for (int nn = 0; nn < 4; ++nn) acc[nn] = (f32x4){0.f, 0.f, 0.f, 0.f};
    const int srow = t >> 2, sg = t & 3;
    const ushort* wsrc = w16 + (size_t)(o0 + srow) * DIMC + sg * 8;
    const ushort* xsrc = xt + ((size_t)b * N_SEQ + n0 + srow) * DIMC + sg * 8;
    uint4 wreg = *(const uint4*)wsrc;
    uint4 xreg = *(const uint4*)xsrc;
    for (int k0 = 0; k0 < DIMC; k0 += 32) {
        __builtin_amdgcn_s_barrier();
        __builtin_amdgcn_sched_barrier(0);
        *(uint4*)(Wls + sg * 520 + srow * 8) = wreg;
        *(uint4*)(Xls + sg * 520 + srow * 8) = xreg;
        if (k0 + 32 < DIMC) {
            wreg = *(const uint4*)(wsrc + k0 + 32);
            xreg = *(const uint4*)(xsrc + k0 + 32);
        }
        asm volatile("s_waitcnt lgkmcnt(0)" ::: "memory");
        __builtin_amdgcn_s_barrier();
        __builtin_amdgcn_sched_barrier(0);
        bf16x8 af = *(const bf16x8*)(Wls + g * 520 + (16 * w + q15) * 8);
        __builtin_amdgcn_s_setprio(1);
#pragma unroll
        for (int nn = 0; nn < 4; ++nn) {
            bf16x8 bfr = *(const bf16x8*)(Xls + g * 520 + (16 * nn + q15) * 8);
            acc[nn] = __builtin_amdgcn_mfma_f32_16x16x32_bf16(af, bfr, acc[nn], 0, 0, 0);
        }
        __builtin_amdgcn_s_setprio(0);
    }
    const int oatom = o0 + 16 * w;
    const int t_idx = oatom >> 8;
    const int h = (oatom >> 5) & 7;
    const int bh = b * 8 + h;
    const int d0 = (oatom & 31) + 4 * g;
    if (t_idx < 2) {
        ushort* dst = ws16 + (size_t)t_idx * 2097152 + (size_t)bh * 65536
                      + (size_t)(d0 >> 3) * 16384 + (d0 & 7);
#pragma unroll
        for (int nn = 0; nn < 4; ++nn) {
            const int n_ = n0 + 16 * nn + q15;
            ushort4 p;
            p.x = f2bf(acc[nn][0]); p.y = f2bf(acc[nn][1]);
            p.z = f2bf(acc[nn][2]); p.w = f2bf(acc[nn][3]);
            *(ushort4*)(dst + (size_t)n_ * 8) = p;
        }
    } else {
        ushort* dst = ws16 + (size_t)4194304 + (size_t)bh * 65536;
#pragma unroll
        for (int nn = 0; nn < 4; ++nn) {
            const int n_ = n0 + 16 * nn + q15;
            ushort* dd = dst + (size_t)(n_ >> 3) * 256 + (n_ & 7);
            dd[(d0 + 0) * 8] = f2bf(acc[nn][0]);
            dd[(d0 + 1) * 8] = f2bf(acc[nn][1]);
            dd[(d0 + 2) * 8] = f2bf(acc[nn][2]);
            dd[(d0 + 3) * 8] = f2bf(acc[nn][3]);
        }
    }
}

// ---------------------------------------------------------------------------
// k2 from bf16 values, prescaled by C2F^2
// ---------------------------------------------------------------------------
__global__ void sq_kernel(const ushort* __restrict__ ws16, float* __restrict__ k2) {
    const int idx = blockIdx.x * 256 + threadIdx.x;
    const int bh = idx >> 11, n = idx & 2047;
    const ushort* base = ws16 + 2097152 + (size_t)bh * 65536 + (size_t)n * 8;
    float s = 0.f;
#pragma unroll
    for (int g = 0; g < 4; ++g) {
        uint4 v = *(const uint4*)(base + (size_t)g * 16384);
        uint a[4] = {v.x, v.y, v.z, v.w};
#pragma unroll
        for (int e = 0; e < 4; ++e) {
            float lo = bf2f((ushort)(a[e] & 0xffff));
            float hi = bf2f((ushort)(a[e] >> 16));
            s += lo * lo + hi * hi;
        }
    }
    k2[idx] = s * (float)C2F2;
}

// ---------------------------------------------------------------------------
// Flash L2 attention — fully software-pipelined per 64-j half:
//   vf(h) issue | kk(h+1)->alt buffer | kf(h+1) issue | scores(h) [st,kk aged
//   one half] | QK(h+1)->st [kf covered by scores; fills Pls wr->rd gap] |
//   PV(h). st and kf are SINGLE-buffered (lifetimes don't overlap; WAR order
//   enforced by program order); only kk is double-buffered. ~115 VGPR.
// m=0 fixed softmax shift (exact by shift-invariance). Final tail iteration
// overruns kf/kk/QK into in-workspace garbage that is never consumed.
// ---------------------------------------------------------------------------
__global__ __launch_bounds__(256, 4) void attn_kernel(
        const ushort* __restrict__ ws16, const float* __restrict__ k2g,
        ushort* __restrict__ att16) {
    __shared__ __align__(16) ushort Pls[4][16][140];
    const int bid = blockIdx.x;                   // 1024 blocks
    const int sw = (bid & 7) * 128 + (bid >> 3);  // bijective XCD swizzle
    const int q0 = (sw & 31) * 64;
    const int bh = sw >> 5;
    const int b = bh >> 3, h = bh & 7;
    const int tid = threadIdx.x;
    const int l = tid & 63;
    const int w = tid >> 6;
    const int q15 = l & 15;
    const int g = l >> 4;
    const int qrow = q0 + 16 * w + q15;

    const ushort* Qbh = ws16 + (size_t)bh * 65536;
    const ushort* Kf = ws16 + 2097152 + (size_t)bh * 65536
                       + (size_t)g * 16384 + (size_t)q15 * 8;
    const ushort* Vf = ws16 + 4194304 + (size_t)bh * 65536 + (size_t)q15 * 8;
    const float* k2p = k2g + (size_t)bh * 2048 + 4 * g;

    const bf16x8 qf = *(const bf16x8*)(Qbh + (size_t)g * 16384 + (size_t)qrow * 8);
    float q2l = 0.f;
#pragma unroll
    for (int e = 0; e < 8; ++e) {
        float qe = bf2f((ushort)qf[e]);
        q2l = fmaf(qe, qe, q2l);
    }
    q2l += __shfl_xor(q2l, 16);
    q2l += __shfl_xor(q2l, 32);
    const float q2v = q2l * (float)C2F2;

    ushort* plane = &Pls[w][q15][0];
    f32x4 accO[2];
    accO[0] = (f32x4){0.f, 0.f, 0.f, 0.f};
    accO[1] = (f32x4){0.f, 0.f, 0.f, 0.f};
    float lsm = 0.f;

    f32x4 st[4];      // single-buffered: QK(h+1) result, consumed scores(h+1)
    bf16x8 kf[4];     // single-buffered: loaded iter h, consumed QK same iter
    float4 kkA[4], kkB[4];  // double-buffered k2

    // prologue: half 0 (one cold stall on kf, once per block)
#pragma unroll
    for (int k = 0; k < 4; ++k) kkA[k] = *(const float4*)(k2p + 16 * k);
#pragma unroll
    for (int k = 0; k < 4; ++k) kf[k] = *(const bf16x8*)(Kf + (size_t)(16 * k) * 8);
    {
        const f32x4 zz = (f32x4){0.f, 0.f, 0.f, 0.f};
#pragma unroll
        for (int k = 0; k < 4; ++k)
            st[k] = __builtin_amdgcn_mfma_f32_16x16x32_bf16(kf[k], qf, zz, 0, 0, 0);
    }

#define ATTN_ITER(H, KKC, KKN)                                                  \
    {                                                                           \
        const int jb = (H) * 64;                                                \
        const int hp = (H) & 1;                                                 \
        bf16x8 vfr[4];                                                          \
        _Pragma("unroll")                                                       \
        for (int jc = 0; jc < 2; ++jc) {                                        \
            const int c = 8 * (H) + 4 * jc + g;                                 \
            vfr[jc * 2 + 0] = *(const bf16x8*)(Vf + (size_t)c * 256);           \
            vfr[jc * 2 + 1] = *(const bf16x8*)(Vf + (size_t)c * 256 + 128);     \
        }                                                                       \
        _Pragma("unroll")                                                       \
        for (int k = 0; k < 4; ++k)                                             \
            KKN[k] = *(const float4*)(k2p + jb + 64 + 16 * k);                  \
        _Pragma("unroll")                                                       \
        for (int k = 0; k < 4; ++k)                                             \
            kf[k] = *(const bf16x8*)(Kf + (size_t)(jb + 64 + 16 * k) * 8);      \
        float lt = 0.f;                                                         \
        _Pragma("unroll")                                                       \
        for (int k = 0; k < 4; ++k) {                                           \
            float ka[4] = {KKC[k].x, KKC[k].y, KKC[k].z, KKC[k].w};             \
            float pr[4];                                                        \
            _Pragma("unroll")                                                   \
            for (int r = 0; r < 4; ++r) {                                       \
                float a = q2v + ka[r];                                          \
                float d2 = fmaf(-2.f * (float)C2F2, st[k][r], a);               \
                pr[r] = fast_exp2_neg(fast_sqrt(fmaxf(d2, 1e-12f)));            \
            }                                                                   \
            lt += (pr[0] + pr[1]) + (pr[2] + pr[3]);                            \
            uint pk0, pk1;                                                      \
            asm("v_cvt_pk_bf16_f32 %0, %1, %2" : "=v"(pk0) : "v"(pr[0]), "v"(pr[1])); \
            asm("v_cvt_pk_bf16_f32 %0, %1, %2" : "=v"(pk1) : "v"(pr[2]), "v"(pr[3])); \
            uint2 pv; pv.x = pk0; pv.y = pk1;                                   \
            *(uint2*)(plane + 16 * (4 * hp + k) + 4 * g) = pv;                  \
        }                                                                       \
        lsm += lt;                                                              \
        const f32x4 zz = (f32x4){0.f, 0.f, 0.f, 0.f};                           \
        __builtin_amdgcn_s_setprio(1);                                          \
        _Pragma("unroll")                                                       \
        for (int k = 0; k < 4; ++k)                                             \
            st[k] = __builtin_amdgcn_mfma_f32_16x16x32_bf16(kf[k], qf, zz, 0, 0, 0); \
        __builtin_amdgcn_s_setprio(0);                                          \
        __builtin_amdgcn_s_setprio(1);                                          \
        _Pragma("unroll")                                                       \
        for (int jc = 0; jc < 2; ++jc) {                                        \
            bf16x8 pf = *(const bf16x8*)(plane + 32 * (2 * hp + jc) + 8 * g);   \
            accO[0] = __builtin_amdgcn_mfma_f32_16x16x32_bf16(vfr[jc * 2 + 0], pf, accO[0], 0, 0, 0); \
            accO[1] = __builtin_amdgcn_mfma_f32_16x16x32_bf16(vfr[jc * 2 + 1], pf, accO[1], 0, 0, 0); \
        }                                                                       \
        __builtin_amdgcn_s_setprio(0);                                          \
    }

#pragma unroll 1
    for (int hh = 0; hh < 32; hh += 2) {
        ATTN_ITER(hh, kkA, kkB)
        ATTN_ITER(hh + 1, kkB, kkA)
    }
#undef ATTN_ITER

    lsm += __shfl_xor(lsm, 16);
    lsm += __shfl_xor(lsm, 32);
    const float invl = 1.f / lsm;
    ushort* dst = att16 + ((size_t)(b * N_SEQ + qrow)) * INNER + h * 32 + 4 * g;
#pragma unroll
    for (int d = 0; d < 2; ++d) {
        ushort4 o;
        o.x = f2bf(accO[d][0] * invl); o.y = f2bf(accO[d][1] * invl);
        o.z = f2bf(accO[d][2] * invl); o.w = f2bf(accO[d][3] * invl);
        *(ushort4*)(dst + d * 16) = o;
    }
}

// ---------------------------------------------------------------------------
// Output projection, bf16 MFMA
// ---------------------------------------------------------------------------
__global__ __launch_bounds__(256) void out_mfma(const ushort* __restrict__ att16,
        const ushort* __restrict__ wo16, const float* __restrict__ bias,
        float* __restrict__ out) {
    __shared__ __align__(16) ushort Wls[4 * 520];
    __shared__ __align__(16) ushort Als[4 * 520];
    const int b = blockIdx.z;
    const int o0 = blockIdx.y * 64;
    const int n0 = blockIdx.x * 64;
    const int t = threadIdx.x;
    const int l = t & 63, w = t >> 6;
    const int q15 = l & 15, g = l >> 4;
    f32x4 acc[4];
#pragma unroll
    for (int nn = 0; nn < 4; ++nn) acc[nn] = (f32x4){0.f, 0.f, 0.f, 0.f};
    const int srow = t >> 2, sg = t & 3;
    const ushort* wsrc = wo16 + (size_t)(o0 + srow) * INNER + sg * 8;
    const ushort* asrc = att16 + ((size_t)b * N_SEQ + n0 + srow) * INNER + sg * 8;
    uint4 wreg = *(const uint4*)wsrc;
    uint4 areg = *(const uint4*)asrc;
    for (int k0 = 0; k0 < INNER; k0 += 32) {
        __builtin_amdgcn_s_barrier();
        __builtin_amdgcn_sched_barrier(0);
        *(uint4*)(Wls + sg * 520 + srow * 8) = wreg;
        *(uint4*)(Als + sg * 520 + srow * 8) = areg;
        if (k0 + 32 < INNER) {
            wreg = *(const uint4*)(wsrc + k0 + 32);
            areg = *(const uint4*)(asrc + k0 + 32);
        }
        asm volatile("s_waitcnt lgkmcnt(0)" ::: "memory");
        __builtin_amdgcn_s_barrier();
        __builtin_amdgcn_sched_barrier(0);
        bf16x8 af = *(const bf16x8*)(Wls + g * 520 + (16 * w + q15) * 8);
        __builtin_amdgcn_s_setprio(1);
#pragma unroll
        for (int nn = 0; nn < 4; ++nn) {
            bf16x8 bfr = *(const bf16x8*)(Als + g * 520 + (16 * nn + q15) * 8);
            acc[nn] = __builtin_amdgcn_mfma_f32_16x16x32_bf16(af, bfr, acc[nn], 0, 0, 0);
        }
        __builtin_amdgcn_s_setprio(0);
    }
    const int obase = o0 + 16 * w + 4 * g;
    float4 bi = *(const float4*)(bias + obase);
    float* ob = out + ((size_t)b * DIMC + obase) * N_SEQ;
#pragma unroll
    for (int nn = 0; nn < 4; ++nn) {
        const int n_ = n0 + 16 * nn + q15;
        ob[0 * N_SEQ + n_] = acc[nn][0] + bi.x;
        ob[1 * N_SEQ + n_] = acc[nn][1] + bi.y;
        ob[2 * N_SEQ + n_] = acc[nn][2] + bi.z;
        ob[3 * N_SEQ + n_] = acc[nn][3] + bi.w;
    }
}

extern "C" void kernel_launch(void* const* d_in, const int* in_sizes, int n_in,
                              void* d_out, int out_size, void* d_ws, size_t ws_size,
                              hipStream_t stream) {
    const float* x = (const float*)d_in[0];
    const float* w_qkv = (const float*)d_in[1];
    const float* w_out = (const float*)d_in[2];
    const float* b_out = (const float*)d_in[3];
    ushort* ws16 = (ushort*)d_ws;
    float* k2f = (float*)((char*)d_ws + (12 << 20) + (256 << 10));
    ushort* att16 = (ushort*)((char*)d_ws + (13 << 20));
    ushort* xt16 = (ushort*)((char*)d_ws + (21 << 20));
    ushort* wq16 = (ushort*)((char*)d_ws + (29 << 20));
    ushort* wo16 = (ushort*)((char*)d_ws + (30 << 20));
    float* out = (float*)d_out;

    xpose_cvt<<<dim3(32, 8, 4), 256, 0, stream>>>(x, xt16);
    wcvt2<<<dim3(512), 256, 0, stream>>>(w_qkv, w_out, wq16, wo16);
    qkv_mfma<<<dim3(32, 12, 4), 256, 0, stream>>>(xt16, wq16, ws16);
    sq_kernel<<<dim3(256), 256, 0, stream>>>(ws16, k2f);
    attn_kernel<<<dim3(1024), 256, 0, stream>>>(ws16, k2f, att16);
    out_mfma<<<dim3(32, 8, 4), 256, 0, stream>>>(att16, wo16, b_out, out);
}